// Round 1
// baseline (11327.741 us; speedup 1.0000x reference)
//
#include <hip/hip_runtime.h>
#include <math.h>

// ---------------------------------------------------------------------------
// Sizes (fixed by the problem)
//   input_context  [512][768]   output_context [1024][768]
//   fw_wih [1536][768] fw_whh [1536][512] fw_bih/bhh [1536]
//   bw_wih [1536][768] bw_whh [1536][512] (whh unused: bwd_hs[-1] = one step from h0=0)
//   dec_wih [3072][768] dec_whh [3072][1024] dec_bih/bhh [3072]
//   W_pred [1024][28996]   out [1024][28996] fp32
// ---------------------------------------------------------------------------

#define NWG 64
#define NT 512

__device__ __forceinline__ float sigmoidf_(float x) {
  return 1.0f / (1.0f + __expf(-x));
}

__device__ __forceinline__ float wave_reduce_sum(float v) {
#pragma unroll
  for (int s = 1; s < 64; s <<= 1) v += __shfl_xor(v, s, 64);
  return v;
}

__device__ __forceinline__ float hload(const float* p) {
  return __hip_atomic_load((float*)p, __ATOMIC_RELAXED, __HIP_MEMORY_SCOPE_AGENT);
}
__device__ __forceinline__ void hstore(float* p, float v) {
  __hip_atomic_store(p, v, __ATOMIC_RELAXED, __HIP_MEMORY_SCOPE_AGENT);
}

// Wait until every workgroup's stamp >= target. Wave 0 polls (one coalesced
// load covers all 64 flags), other waves park at the barrier.
__device__ __forceinline__ void wait_all_flags(unsigned* flags, unsigned target) {
  if (threadIdx.x < NWG) {
    while (__hip_atomic_load(&flags[threadIdx.x], __ATOMIC_ACQUIRE,
                             __HIP_MEMORY_SCOPE_AGENT) < target) {
      __builtin_amdgcn_s_sleep(1);
    }
  }
  __syncthreads();
}

// ---------------------------------------------------------------------------
// Persistent recurrence kernel: fw encoder (512 steps) then decoder (1024
// steps). 64 wgs x 512 threads -> 512 waves. fw: 1 hidden unit per wave.
// dec: 2 hidden units per wave. Recurrent weights live in registers for the
// whole kernel. h state ping-pongs through AGENT-scope global buffers; per-wg
// monotone stamps order the steps (stamp t+1 set only after all of this wg's
// step-t reads and writes completed -> depth-2 buffer reuse is safe).
// ---------------------------------------------------------------------------
__global__ __launch_bounds__(NT, 1) void recur_kernel(
    const float* __restrict__ gxfw,    // [512][1536]
    const float* __restrict__ gxdec,   // [1024][3072]
    const float* __restrict__ gxbw,    // [1536]
    const float* __restrict__ whh_fw,  // [1536][512]
    const float* __restrict__ bhh_fw,  // [1536]
    const float* __restrict__ whh_dec, // [3072][1024]
    const float* __restrict__ bhh_dec, // [3072]
    const float* __restrict__ bhh_bw,  // [1536]
    float* hfw,                        // [2][512]  (buffer 0 zeroed by memset)
    float* hdec,                       // [2][1024]
    unsigned* flags,                   // [NWG] (zeroed by memset)
    float* __restrict__ dec_hs)        // [1024][1024]
{
  const int tid = threadIdx.x;
  const int wg = blockIdx.x;
  const int wave = tid >> 6;
  const int lane = tid & 63;

  // backward "encoder" = single GRU cell on input row 511 from h0=0:
  // gh = bhh only. Written before wg0's first RELEASE flag store.
  if (wg == 0) {
    const int j = tid;  // NT == 512 == HIDDEN
    const float r = sigmoidf_(gxbw[j] + bhh_bw[j]);
    const float z = sigmoidf_(gxbw[512 + j] + bhh_bw[512 + j]);
    const float n = tanhf(gxbw[1024 + j] + r * bhh_bw[1024 + j]);
    hstore(&hdec[512 + j], (1.0f - z) * n);
  }

  // ---------------- forward encoder: 512 steps ----------------
  {
    const int u = (wg << 3) + wave;  // 0..511
    const float br = bhh_fw[u], bz = bhh_fw[512 + u], bn = bhh_fw[1024 + u];
    float4 wr[3][2];  // 3 gate rows x 8 f32 per lane, held in regs all steps
#pragma unroll
    for (int g = 0; g < 3; ++g) {
      const float* w = whh_fw + (size_t)(g * 512 + u) * 512;
#pragma unroll
      for (int i = 0; i < 2; ++i)
        wr[g][i] = *(const float4*)&w[(i << 8) + (lane << 2)];
    }
    for (int t = 0; t < 512; ++t) {
      if (t) wait_all_flags(flags, (unsigned)t);
      float* hc = hfw + ((t & 1) << 9);
      float h4[2][4];
#pragma unroll
      for (int i = 0; i < 2; ++i) {
        const int off = (i << 8) + (lane << 2);
#pragma unroll
        for (int j = 0; j < 4; ++j) h4[i][j] = hload(&hc[off + j]);
      }
      float p0 = 0.f, p1 = 0.f, p2 = 0.f;
#pragma unroll
      for (int i = 0; i < 2; ++i) {
        p0 += wr[0][i].x * h4[i][0] + wr[0][i].y * h4[i][1] +
              wr[0][i].z * h4[i][2] + wr[0][i].w * h4[i][3];
        p1 += wr[1][i].x * h4[i][0] + wr[1][i].y * h4[i][1] +
              wr[1][i].z * h4[i][2] + wr[1][i].w * h4[i][3];
        p2 += wr[2][i].x * h4[i][0] + wr[2][i].y * h4[i][1] +
              wr[2][i].z * h4[i][2] + wr[2][i].w * h4[i][3];
      }
      p0 = wave_reduce_sum(p0);
      p1 = wave_reduce_sum(p1);
      p2 = wave_reduce_sum(p2);
      if (lane == 0) {
        const float hold = hload(&hc[u]);
        const float* gx = gxfw + (size_t)t * 1536;
        const float r = sigmoidf_(gx[u] + p0 + br);
        const float z = sigmoidf_(gx[512 + u] + p1 + bz);
        const float n = tanhf(gx[1024 + u] + r * (p2 + bn));
        const float hnew = (1.0f - z) * n + z * hold;
        float* dst = (t < 511) ? (hfw + (((t + 1) & 1) << 9)) : hdec;
        hstore(&dst[u], hnew);
      }
      __syncthreads();  // drains all waves' stores (vmcnt) before the stamp
      if (tid == 0)
        __hip_atomic_store(&flags[wg], (unsigned)(t + 1), __ATOMIC_RELEASE,
                           __HIP_MEMORY_SCOPE_AGENT);
    }
  }

  // ---------------- decoder: 1024 steps ----------------
  {
    const int u0 = (wg << 4) + (wave << 1);  // 2 units per wave
    float bb0[2], bb1[2], bb2[2];
    float4 wr[2][3][4];  // 2 units x 3 gates x 16 f32 per lane
#pragma unroll
    for (int uu = 0; uu < 2; ++uu) {
      bb0[uu] = bhh_dec[u0 + uu];
      bb1[uu] = bhh_dec[1024 + u0 + uu];
      bb2[uu] = bhh_dec[2048 + u0 + uu];
#pragma unroll
      for (int g = 0; g < 3; ++g) {
        const float* w = whh_dec + (size_t)(g * 1024 + u0 + uu) * 1024;
#pragma unroll
        for (int i = 0; i < 4; ++i)
          wr[uu][g][i] = *(const float4*)&w[(i << 8) + (lane << 2)];
      }
    }
    for (int t = 0; t < 1024; ++t) {
      wait_all_flags(flags, (unsigned)(512 + t));
      float* hc = hdec + ((t & 1) << 10);
      float h4[4][4];
#pragma unroll
      for (int i = 0; i < 4; ++i) {
        const int off = (i << 8) + (lane << 2);
#pragma unroll
        for (int j = 0; j < 4; ++j) h4[i][j] = hload(&hc[off + j]);
      }
#pragma unroll
      for (int uu = 0; uu < 2; ++uu) {
        float p0 = 0.f, p1 = 0.f, p2 = 0.f;
#pragma unroll
        for (int i = 0; i < 4; ++i) {
          p0 += wr[uu][0][i].x * h4[i][0] + wr[uu][0][i].y * h4[i][1] +
                wr[uu][0][i].z * h4[i][2] + wr[uu][0][i].w * h4[i][3];
          p1 += wr[uu][1][i].x * h4[i][0] + wr[uu][1][i].y * h4[i][1] +
                wr[uu][1][i].z * h4[i][2] + wr[uu][1][i].w * h4[i][3];
          p2 += wr[uu][2][i].x * h4[i][0] + wr[uu][2][i].y * h4[i][1] +
                wr[uu][2][i].z * h4[i][2] + wr[uu][2][i].w * h4[i][3];
        }
        p0 = wave_reduce_sum(p0);
        p1 = wave_reduce_sum(p1);
        p2 = wave_reduce_sum(p2);
        if (lane == 0) {
          const int u = u0 + uu;
          const float hold = hload(&hc[u]);
          const float* gx = gxdec + (size_t)t * 3072;
          const float r = sigmoidf_(gx[u] + p0 + bb0[uu]);
          const float z = sigmoidf_(gx[1024 + u] + p1 + bb1[uu]);
          const float n = tanhf(gx[2048 + u] + r * (p2 + bb2[uu]));
          const float hnew = (1.0f - z) * n + z * hold;
          hstore(&hdec[(((t + 1) & 1) << 10) + u], hnew);
          dec_hs[(size_t)t * 1024 + u] = hnew;  // plain store, read next kernel
        }
      }
      __syncthreads();
      if (tid == 0)
        __hip_atomic_store(&flags[wg], (unsigned)(513 + t), __ATOMIC_RELEASE,
                           __HIP_MEMORY_SCOPE_AGENT);
    }
  }
}

// ---------------------------------------------------------------------------
// fp32 GEMM, 128x128 tile, BK=16, 256 threads, 8x8 microtile.
//   BT=1: C[M,N] = Amap[M,K] * B[N,K]^T + bias   (input projections)
//   BT=0: C[M,N] = A[M,K]   * B[K,N]   (+bias)   (vocab projection)
// rowmode: 0 identity, 1 decoder shift (row m -> max(m-1,0)), 2 fixed row.
// ---------------------------------------------------------------------------
#define GBM 128
#define GBN 128
#define GBK 16
#define GLDS 132  // +4 pad: 16B-aligned rows, no serializing bank conflicts

template <int BT>
__global__ __launch_bounds__(256) void gemm128(
    const float* __restrict__ A, const float* __restrict__ B,
    const float* __restrict__ bias, float* __restrict__ C, int M, int N, int K,
    int rowmode, int fixedrow) {
  __shared__ float As[GBK][GLDS];
  __shared__ float Bs[GBK][GLDS];
  const int tid = threadIdx.x;
  const int n0 = blockIdx.x * GBN;
  const int m0 = blockIdx.y * GBM;
  const int tx = tid & 15;
  const int ty = tid >> 4;
  float acc[8][8];
#pragma unroll
  for (int i = 0; i < 8; ++i)
#pragma unroll
    for (int j = 0; j < 8; ++j) acc[i][j] = 0.f;

  const int fl = tid >> 1;        // 0..127
  const int fk = (tid & 1) << 3;  // 0 or 8
  const int am = m0 + fl;
  int asrow = am;
  if (rowmode == 1) asrow = (am == 0) ? 0 : am - 1;
  else if (rowmode == 2) asrow = fixedrow;
  const bool aok = (am < M);
  const bool nfull = (n0 + GBN <= N);

  for (int k0 = 0; k0 < K; k0 += GBK) {
    {  // A fill (transposed into LDS: As[k][m])
      float4 v0 = make_float4(0.f, 0.f, 0.f, 0.f), v1 = v0;
      if (aok) {
        const float* p = A + (size_t)asrow * K + k0 + fk;
        v0 = *(const float4*)p;
        v1 = *(const float4*)(p + 4);
      }
      As[fk + 0][fl] = v0.x; As[fk + 1][fl] = v0.y;
      As[fk + 2][fl] = v0.z; As[fk + 3][fl] = v0.w;
      As[fk + 4][fl] = v1.x; As[fk + 5][fl] = v1.y;
      As[fk + 6][fl] = v1.z; As[fk + 7][fl] = v1.w;
    }
    if (BT) {  // B is [N,K]: Bs[k][n] = B[n][k] (transposed fill)
      const int bn = n0 + fl;
      float4 v0 = make_float4(0.f, 0.f, 0.f, 0.f), v1 = v0;
      if (bn < N) {
        const float* p = B + (size_t)bn * K + k0 + fk;
        v0 = *(const float4*)p;
        v1 = *(const float4*)(p + 4);
      }
      Bs[fk + 0][fl] = v0.x; Bs[fk + 1][fl] = v0.y;
      Bs[fk + 2][fl] = v0.z; Bs[fk + 3][fl] = v0.w;
      Bs[fk + 4][fl] = v1.x; Bs[fk + 5][fl] = v1.y;
      Bs[fk + 6][fl] = v1.z; Bs[fk + 7][fl] = v1.w;
    } else {  // B is [K,N]: coalesced fill
      const int kl = tid >> 4;
      const int nq = (tid & 15) << 3;
      const float* p = B + (size_t)(k0 + kl) * N + n0 + nq;
      if (nfull) {
        *(float4*)&Bs[kl][nq] = *(const float4*)p;
        *(float4*)&Bs[kl][nq + 4] = *(const float4*)(p + 4);
      } else {
#pragma unroll
        for (int j = 0; j < 8; ++j)
          Bs[kl][nq + j] = (n0 + nq + j < N) ? p[j] : 0.f;
      }
    }
    __syncthreads();
#pragma unroll
    for (int k = 0; k < GBK; ++k) {
      const float4 a0 = *(const float4*)&As[k][ty << 3];
      const float4 a1 = *(const float4*)&As[k][(ty << 3) + 4];
      const float4 b0 = *(const float4*)&Bs[k][tx << 3];
      const float4 b1 = *(const float4*)&Bs[k][(tx << 3) + 4];
      const float av[8] = {a0.x, a0.y, a0.z, a0.w, a1.x, a1.y, a1.z, a1.w};
      const float bv[8] = {b0.x, b0.y, b0.z, b0.w, b1.x, b1.y, b1.z, b1.w};
#pragma unroll
      for (int i = 0; i < 8; ++i)
#pragma unroll
        for (int j = 0; j < 8; ++j) acc[i][j] += av[i] * bv[j];
    }
    __syncthreads();
  }

  const int mb = m0 + (ty << 3);
  const int nb = n0 + (tx << 3);
#pragma unroll
  for (int i = 0; i < 8; ++i) {
    const int m = mb + i;
    if (m >= M) continue;
    float o[8];
#pragma unroll
    for (int j = 0; j < 8; ++j) o[j] = acc[i][j];
    if (nfull) {
      if (bias) {
#pragma unroll
        for (int j = 0; j < 8; ++j) o[j] += bias[nb + j];
      }
      *(float4*)&C[(size_t)m * N + nb] = make_float4(o[0], o[1], o[2], o[3]);
      *(float4*)&C[(size_t)m * N + nb + 4] = make_float4(o[4], o[5], o[6], o[7]);
    } else {
#pragma unroll
      for (int j = 0; j < 8; ++j) {
        const int n = nb + j;
        if (n < N) C[(size_t)m * N + n] = o[j] + (bias ? bias[n] : 0.f);
      }
    }
  }
}

// ---------------------------------------------------------------------------
// Workspace layout (floats):
//   [0,64)                flags (as unsigned)
//   [64,1088)             hfw[2][512]
//   [1088,3136)           hdec[2][1024]
//   [3136,4672)           gxbw[1536]
//   [4672,791104)         gxfw[512*1536]
//   [791104,3936832)      gxdec[1024*3072]
//   [3936832,4985408)     dec_hs[1024*1024]
// total ~19.9 MB
// ---------------------------------------------------------------------------
extern "C" void kernel_launch(void* const* d_in, const int* in_sizes, int n_in,
                              void* d_out, int out_size, void* d_ws,
                              size_t ws_size, hipStream_t stream) {
  (void)in_sizes; (void)n_in; (void)out_size; (void)ws_size;
  const float* input_context  = (const float*)d_in[0];
  const float* output_context = (const float*)d_in[1];
  const float* fw_wih = (const float*)d_in[2];
  const float* fw_whh = (const float*)d_in[3];
  const float* fw_bih = (const float*)d_in[4];
  const float* fw_bhh = (const float*)d_in[5];
  const float* bw_wih = (const float*)d_in[6];
  // d_in[7] bw_whh unused: backward contribution is a single step from h0=0
  const float* bw_bih = (const float*)d_in[8];
  const float* bw_bhh = (const float*)d_in[9];
  const float* dec_wih = (const float*)d_in[10];
  const float* dec_whh = (const float*)d_in[11];
  const float* dec_bih = (const float*)d_in[12];
  const float* dec_bhh = (const float*)d_in[13];
  const float* W_pred  = (const float*)d_in[14];
  float* out = (float*)d_out;

  float* wsf = (float*)d_ws;
  unsigned* flags = (unsigned*)wsf;      // 64
  float* hfw   = wsf + 64;               // 2*512
  float* hdec  = wsf + 64 + 1024;        // 2*1024
  float* gxbw  = wsf + 3136;             // 1536
  float* gxfw  = wsf + 4672;             // 512*1536
  float* gxdec = gxfw + 512 * 1536;      // 1024*3072
  float* dec_hs = gxdec + 1024 * 3072;   // 1024*1024

  // zero flags + h buffers (h0 = 0 for the forward encoder)
  hipMemsetAsync(d_ws, 0, 3136 * sizeof(float), stream);

  const dim3 blk(256);
  // gx projections: C = A * wih^T + bih
  gemm128<1><<<dim3(12, 4), blk, 0, stream>>>(
      input_context, fw_wih, fw_bih, gxfw, 512, 1536, 768, 0, 0);
  gemm128<1><<<dim3(12, 1), blk, 0, stream>>>(
      input_context, bw_wih, bw_bih, gxbw, 1, 1536, 768, 2, 511);
  gemm128<1><<<dim3(24, 8), blk, 0, stream>>>(
      output_context, dec_wih, dec_bih, gxdec, 1024, 3072, 768, 1, 0);

  recur_kernel<<<dim3(NWG), dim3(NT), 0, stream>>>(
      gxfw, gxdec, gxbw, fw_whh, fw_bhh, dec_whh, dec_bhh, bw_bhh, hfw, hdec,
      flags, dec_hs);

  // vocab projection: out = dec_hs * W_pred
  gemm128<0><<<dim3(227, 8), blk, 0, stream>>>(
      dec_hs, W_pred, nullptr, out, 1024, 28996, 1024, 0, 0);
}

// Round 2
// 7016.384 us; speedup vs baseline: 1.6145x; 1.6145x over previous
//
#include <hip/hip_runtime.h>
#include <math.h>

// ---------------------------------------------------------------------------
// Sizes (fixed by the problem)
//   input_context  [512][768]   output_context [1024][768]
//   fw_wih [1536][768] fw_whh [1536][512] fw_bih/bhh [1536]
//   bw_wih [1536][768] (whh unused: bwd_hs[-1] = one step from h0=0)
//   dec_wih [3072][768] dec_whh [3072][1024] dec_bih/bhh [3072]
//   W_pred [1024][28996]   out [1024][28996] fp32
// ---------------------------------------------------------------------------

typedef unsigned long long u64;

#define NWG 64
#define NT 512

__device__ __forceinline__ float sigmoidf_(float x) {
  return 1.0f / (1.0f + __expf(-x));
}

__device__ __forceinline__ float wave_reduce_sum(float v) {
#pragma unroll
  for (int s = 1; s < 64; s <<= 1) v += __shfl_xor(v, s, 64);
  return v;
}

// (tag, h) packed in one 8-byte word: a single relaxed agent-scope atomic
// store publishes value + readiness together; no fences, no flag array.
__device__ __forceinline__ u64 pack_ht(float h, unsigned tag) {
  union { float f; unsigned u; } c; c.f = h;
  return ((u64)tag << 32) | (u64)c.u;
}
__device__ __forceinline__ float pk_h(u64 v) {
  union { unsigned u; float f; } c; c.u = (unsigned)v; return c.f;
}
__device__ __forceinline__ void astore(u64* p, u64 v) {
  __hip_atomic_store(p, v, __ATOMIC_RELAXED, __HIP_MEMORY_SCOPE_AGENT);
}
__device__ __forceinline__ u64 aload(const u64* p) {
  return __hip_atomic_load((u64*)p, __ATOMIC_RELAXED, __HIP_MEMORY_SCOPE_AGENT);
}

// ---------------------------------------------------------------------------
// Persistent recurrence kernel. 64 wgs x 512 threads.
// fw encoder: 512 steps, 1 unit/wave. decoder: 1024 steps, 2 units/wave.
// Recurrent weights in registers for the whole kernel.
// Per step: wave0 polls the (tag,h) buffer until all tags >= t, stages h into
// LDS (ping-pong); barrier; all waves compute from LDS; lane0 publishes
// (h_new, t+1) with one 8B atomic store. Depth-2 global ping-pong is safe:
// tag t+2 overwrites a slot only after all wgs published t+1, which implies
// their reads of tag t from that slot completed.
// ---------------------------------------------------------------------------
__global__ __launch_bounds__(NT) void recur_kernel(
    const float* __restrict__ gxfw,    // [512][1536]
    const float* __restrict__ gxdec,   // [1024][3072]
    const float* __restrict__ gxbw,    // [1536]
    const float* __restrict__ whh_fw,  // [1536][512]
    const float* __restrict__ bhh_fw,  // [1536]
    const float* __restrict__ whh_dec, // [3072][1024]
    const float* __restrict__ bhh_dec, // [3072]
    const float* __restrict__ bhh_bw,  // [1536]
    u64* fwbuf,                        // [2][512]  zeroed: (h=0, tag=0)
    u64* decbuf,                       // [2][1024] zeroed
    float* __restrict__ dec_hs)        // [1024][1024]
{
  __shared__ float Hs[2048];  // ping-pong: fw 2x512 (low half), dec 2x1024
  const int tid = threadIdx.x;
  const int wg = blockIdx.x;
  const int wave = tid >> 6;
  const int lane = tid & 63;

  // backward "encoder" = one GRU cell on input row 511 from h0=0 (gh = bhh).
  // Published with tag 512 into the decoder h buffer, slot 0.
  if (wg == 0) {
    const int j = tid;  // NT == 512 == HIDDEN
    const float r = sigmoidf_(gxbw[j] + bhh_bw[j]);
    const float z = sigmoidf_(gxbw[512 + j] + bhh_bw[512 + j]);
    const float n = tanhf(gxbw[1024 + j] + r * bhh_bw[1024 + j]);
    astore(&decbuf[512 + j], pack_ht((1.0f - z) * n, 512u));
  }

  // ---------------- forward encoder: 512 steps ----------------
  {
    const int u = (wg << 3) + wave;  // 0..511, one unit per wave
    const float br = bhh_fw[u], bz = bhh_fw[512 + u], bn = bhh_fw[1024 + u];
    float4 wr[3][2];  // 3 gate rows x 8 f32 per lane
#pragma unroll
    for (int g = 0; g < 3; ++g) {
      const float* w = whh_fw + (size_t)(g * 512 + u) * 512;
#pragma unroll
      for (int i = 0; i < 2; ++i)
        wr[g][i] = *(const float4*)&w[(i << 8) + (lane << 2)];
    }
    for (int t = 0; t < 512; ++t) {
      const u64* src = fwbuf + ((t & 1) << 9);
      float* hs = Hs + ((t & 1) << 9);
      if (wave == 0) {  // poll + stage into LDS
        u64 v[8];
        for (;;) {
          bool ok = true;
#pragma unroll
          for (int j = 0; j < 8; ++j) {
            v[j] = aload(src + (j << 6) + lane);
            ok &= ((unsigned)(v[j] >> 32) >= (unsigned)t);
          }
          if (__all(ok)) break;
        }
#pragma unroll
        for (int j = 0; j < 8; ++j) hs[(j << 6) + lane] = pk_h(v[j]);
      }
      // issue gx loads before the barrier (latency hidden under the wait)
      const float* gx = gxfw + (size_t)t * 1536;
      const float g0 = gx[u], g1 = gx[512 + u], g2 = gx[1024 + u];
      __syncthreads();
      const float4 ha = *(const float4*)&hs[lane << 2];
      const float4 hb = *(const float4*)&hs[256 + (lane << 2)];
      float p0 = wr[0][0].x * ha.x + wr[0][0].y * ha.y + wr[0][0].z * ha.z +
                 wr[0][0].w * ha.w + wr[0][1].x * hb.x + wr[0][1].y * hb.y +
                 wr[0][1].z * hb.z + wr[0][1].w * hb.w;
      float p1 = wr[1][0].x * ha.x + wr[1][0].y * ha.y + wr[1][0].z * ha.z +
                 wr[1][0].w * ha.w + wr[1][1].x * hb.x + wr[1][1].y * hb.y +
                 wr[1][1].z * hb.z + wr[1][1].w * hb.w;
      float p2 = wr[2][0].x * ha.x + wr[2][0].y * ha.y + wr[2][0].z * ha.z +
                 wr[2][0].w * ha.w + wr[2][1].x * hb.x + wr[2][1].y * hb.y +
                 wr[2][1].z * hb.z + wr[2][1].w * hb.w;
      p0 = wave_reduce_sum(p0);
      p1 = wave_reduce_sum(p1);
      p2 = wave_reduce_sum(p2);
      if (lane == 0) {
        const float hold = hs[u];
        const float r = sigmoidf_(g0 + p0 + br);
        const float z = sigmoidf_(g1 + p1 + bz);
        const float n = tanhf(g2 + r * (p2 + bn));
        const float hnew = (1.0f - z) * n + z * hold;
        if (t < 511)
          astore(fwbuf + (((t + 1) & 1) << 9) + u, pack_ht(hnew, (unsigned)(t + 1)));
        else
          astore(decbuf + u, pack_ht(hnew, 512u));  // slot 0, tag 512
      }
    }
  }
  __syncthreads();  // LDS region handoff fw -> dec

  // ---------------- decoder: 1024 steps ----------------
  {
    const int u0 = (wg << 4) + (wave << 1);  // 2 units per wave
    float bb0[2], bb1[2], bb2[2];
    float4 wr[2][3][4];  // 2 units x 3 gates x 16 f32 per lane
#pragma unroll
    for (int uu = 0; uu < 2; ++uu) {
      bb0[uu] = bhh_dec[u0 + uu];
      bb1[uu] = bhh_dec[1024 + u0 + uu];
      bb2[uu] = bhh_dec[2048 + u0 + uu];
#pragma unroll
      for (int g = 0; g < 3; ++g) {
        const float* w = whh_dec + (size_t)(g * 1024 + u0 + uu) * 1024;
#pragma unroll
        for (int i = 0; i < 4; ++i)
          wr[uu][g][i] = *(const float4*)&w[(i << 8) + (lane << 2)];
      }
    }
    for (int td = 0; td < 1024; ++td) {
      const int t = 512 + td;  // global tag
      const u64* src = decbuf + ((t & 1) << 10);
      float* hs = Hs + ((t & 1) << 10);
      if (wave == 0) {
        u64 v[16];
        for (;;) {
          bool ok = true;
#pragma unroll
          for (int j = 0; j < 16; ++j) {
            v[j] = aload(src + (j << 6) + lane);
            ok &= ((unsigned)(v[j] >> 32) >= (unsigned)t);
          }
          if (__all(ok)) break;
        }
#pragma unroll
        for (int j = 0; j < 16; ++j) hs[(j << 6) + lane] = pk_h(v[j]);
      }
      const float* gx = gxdec + (size_t)td * 3072;
      float ga[2], gb[2], gc[2];
#pragma unroll
      for (int uu = 0; uu < 2; ++uu) {
        ga[uu] = gx[u0 + uu];
        gb[uu] = gx[1024 + u0 + uu];
        gc[uu] = gx[2048 + u0 + uu];
      }
      __syncthreads();
      float4 h4[4];
#pragma unroll
      for (int i = 0; i < 4; ++i)
        h4[i] = *(const float4*)&hs[(i << 8) + (lane << 2)];
#pragma unroll
      for (int uu = 0; uu < 2; ++uu) {
        float p0 = 0.f, p1 = 0.f, p2 = 0.f;
#pragma unroll
        for (int i = 0; i < 4; ++i) {
          p0 += wr[uu][0][i].x * h4[i].x + wr[uu][0][i].y * h4[i].y +
                wr[uu][0][i].z * h4[i].z + wr[uu][0][i].w * h4[i].w;
          p1 += wr[uu][1][i].x * h4[i].x + wr[uu][1][i].y * h4[i].y +
                wr[uu][1][i].z * h4[i].z + wr[uu][1][i].w * h4[i].w;
          p2 += wr[uu][2][i].x * h4[i].x + wr[uu][2][i].y * h4[i].y +
                wr[uu][2][i].z * h4[i].z + wr[uu][2][i].w * h4[i].w;
        }
        p0 = wave_reduce_sum(p0);
        p1 = wave_reduce_sum(p1);
        p2 = wave_reduce_sum(p2);
        if (lane == 0) {
          const int u = u0 + uu;
          const float hold = hs[u];
          const float r = sigmoidf_(ga[uu] + p0 + bb0[uu]);
          const float z = sigmoidf_(gb[uu] + p1 + bb1[uu]);
          const float n = tanhf(gc[uu] + r * (p2 + bb2[uu]));
          const float hnew = (1.0f - z) * n + z * hold;
          astore(decbuf + (((t + 1) & 1) << 10) + u,
                 pack_ht(hnew, (unsigned)(t + 1)));
          dec_hs[(size_t)td * 1024 + u] = hnew;  // plain store, next kernel
        }
      }
    }
  }
}

// ---------------------------------------------------------------------------
// fp32 GEMM, 128x128 tile, BK=16, 256 threads, 8x8 microtile.
//   BT=1: C[M,N] = Amap[M,K] * B[N,K]^T + bias   (input projections)
//   BT=0: C[M,N] = A[M,K]   * B[K,N]   (+bias)   (vocab projection)
// rowmode: 0 identity, 1 decoder shift (row m -> max(m-1,0)), 2 fixed row.
// ---------------------------------------------------------------------------
#define GBM 128
#define GBN 128
#define GBK 16
#define GLDS 132  // +4 pad

template <int BT>
__global__ __launch_bounds__(256) void gemm128(
    const float* __restrict__ A, const float* __restrict__ B,
    const float* __restrict__ bias, float* __restrict__ C, int M, int N, int K,
    int rowmode, int fixedrow) {
  __shared__ float As[GBK][GLDS];
  __shared__ float Bs[GBK][GLDS];
  const int tid = threadIdx.x;
  const int n0 = blockIdx.x * GBN;
  const int m0 = blockIdx.y * GBM;
  const int tx = tid & 15;
  const int ty = tid >> 4;
  float acc[8][8];
#pragma unroll
  for (int i = 0; i < 8; ++i)
#pragma unroll
    for (int j = 0; j < 8; ++j) acc[i][j] = 0.f;

  const int fl = tid >> 1;
  const int fk = (tid & 1) << 3;
  const int am = m0 + fl;
  int asrow = am;
  if (rowmode == 1) asrow = (am == 0) ? 0 : am - 1;
  else if (rowmode == 2) asrow = fixedrow;
  const bool aok = (am < M);
  const bool nfull = (n0 + GBN <= N);

  for (int k0 = 0; k0 < K; k0 += GBK) {
    {
      float4 v0 = make_float4(0.f, 0.f, 0.f, 0.f), v1 = v0;
      if (aok) {
        const float* p = A + (size_t)asrow * K + k0 + fk;
        v0 = *(const float4*)p;
        v1 = *(const float4*)(p + 4);
      }
      As[fk + 0][fl] = v0.x; As[fk + 1][fl] = v0.y;
      As[fk + 2][fl] = v0.z; As[fk + 3][fl] = v0.w;
      As[fk + 4][fl] = v1.x; As[fk + 5][fl] = v1.y;
      As[fk + 6][fl] = v1.z; As[fk + 7][fl] = v1.w;
    }
    if (BT) {
      const int bn = n0 + fl;
      float4 v0 = make_float4(0.f, 0.f, 0.f, 0.f), v1 = v0;
      if (bn < N) {
        const float* p = B + (size_t)bn * K + k0 + fk;
        v0 = *(const float4*)p;
        v1 = *(const float4*)(p + 4);
      }
      Bs[fk + 0][fl] = v0.x; Bs[fk + 1][fl] = v0.y;
      Bs[fk + 2][fl] = v0.z; Bs[fk + 3][fl] = v0.w;
      Bs[fk + 4][fl] = v1.x; Bs[fk + 5][fl] = v1.y;
      Bs[fk + 6][fl] = v1.z; Bs[fk + 7][fl] = v1.w;
    } else {
      const int kl = tid >> 4;
      const int nq = (tid & 15) << 3;
      const float* p = B + (size_t)(k0 + kl) * N + n0 + nq;
      if (nfull) {
        *(float4*)&Bs[kl][nq] = *(const float4*)p;
        *(float4*)&Bs[kl][nq + 4] = *(const float4*)(p + 4);
      } else {
#pragma unroll
        for (int j = 0; j < 8; ++j)
          Bs[kl][nq + j] = (n0 + nq + j < N) ? p[j] : 0.f;
      }
    }
    __syncthreads();
#pragma unroll
    for (int k = 0; k < GBK; ++k) {
      const float4 a0 = *(const float4*)&As[k][ty << 3];
      const float4 a1 = *(const float4*)&As[k][(ty << 3) + 4];
      const float4 b0 = *(const float4*)&Bs[k][tx << 3];
      const float4 b1 = *(const float4*)&Bs[k][(tx << 3) + 4];
      const float av[8] = {a0.x, a0.y, a0.z, a0.w, a1.x, a1.y, a1.z, a1.w};
      const float bv[8] = {b0.x, b0.y, b0.z, b0.w, b1.x, b1.y, b1.z, b1.w};
#pragma unroll
      for (int i = 0; i < 8; ++i)
#pragma unroll
        for (int j = 0; j < 8; ++j) acc[i][j] += av[i] * bv[j];
    }
    __syncthreads();
  }

  const int mb = m0 + (ty << 3);
  const int nb = n0 + (tx << 3);
#pragma unroll
  for (int i = 0; i < 8; ++i) {
    const int m = mb + i;
    if (m >= M) continue;
    float o[8];
#pragma unroll
    for (int j = 0; j < 8; ++j) o[j] = acc[i][j];
    if (nfull) {
      if (bias) {
#pragma unroll
        for (int j = 0; j < 8; ++j) o[j] += bias[nb + j];
      }
      *(float4*)&C[(size_t)m * N + nb] = make_float4(o[0], o[1], o[2], o[3]);
      *(float4*)&C[(size_t)m * N + nb + 4] = make_float4(o[4], o[5], o[6], o[7]);
    } else {
#pragma unroll
      for (int j = 0; j < 8; ++j) {
        const int n = nb + j;
        if (n < N) C[(size_t)m * N + n] = o[j] + (bias ? bias[n] : 0.f);
      }
    }
  }
}

// ---------------------------------------------------------------------------
// Workspace layout (bytes):
//   [0, 8192)        fwbuf  u64[2][512]   (zeroed each launch)
//   [8192, 24576)    decbuf u64[2][1024]  (zeroed each launch)
//   [24576, ...)     gxbw f32[1536], gxfw f32[512*1536],
//                    gxdec f32[1024*3072], dec_hs f32[1024*1024]
// ---------------------------------------------------------------------------
extern "C" void kernel_launch(void* const* d_in, const int* in_sizes, int n_in,
                              void* d_out, int out_size, void* d_ws,
                              size_t ws_size, hipStream_t stream) {
  (void)in_sizes; (void)n_in; (void)out_size; (void)ws_size;
  const float* input_context  = (const float*)d_in[0];
  const float* output_context = (const float*)d_in[1];
  const float* fw_wih = (const float*)d_in[2];
  const float* fw_whh = (const float*)d_in[3];
  const float* fw_bih = (const float*)d_in[4];
  const float* fw_bhh = (const float*)d_in[5];
  const float* bw_wih = (const float*)d_in[6];
  const float* bw_bih = (const float*)d_in[8];
  const float* bw_bhh = (const float*)d_in[9];
  const float* dec_wih = (const float*)d_in[10];
  const float* dec_whh = (const float*)d_in[11];
  const float* dec_bih = (const float*)d_in[12];
  const float* dec_bhh = (const float*)d_in[13];
  const float* W_pred  = (const float*)d_in[14];
  float* out = (float*)d_out;

  u64* fwbuf  = (u64*)d_ws;            // 1024 u64
  u64* decbuf = fwbuf + 1024;          // 2048 u64
  float* wsf  = (float*)d_ws;
  float* gxbw  = wsf + 6144;           // 1536
  float* gxfw  = wsf + 7680;           // 512*1536
  float* gxdec = gxfw + 512 * 1536;    // 1024*3072
  float* dec_hs = gxdec + 1024 * 3072; // 1024*1024

  // zero the (tag,h) buffers: tag=0 (= not ready for t>=1), h0=0 for t=0
  hipMemsetAsync(d_ws, 0, 24576, stream);

  const dim3 blk(256);
  gemm128<1><<<dim3(12, 4), blk, 0, stream>>>(
      input_context, fw_wih, fw_bih, gxfw, 512, 1536, 768, 0, 0);
  gemm128<1><<<dim3(12, 1), blk, 0, stream>>>(
      input_context, bw_wih, bw_bih, gxbw, 1, 1536, 768, 2, 511);
  gemm128<1><<<dim3(24, 8), blk, 0, stream>>>(
      output_context, dec_wih, dec_bih, gxdec, 1024, 3072, 768, 1, 0);

  recur_kernel<<<dim3(NWG), dim3(NT), 0, stream>>>(
      gxfw, gxdec, gxbw, fw_whh, fw_bhh, dec_whh, dec_bhh, bw_bhh,
      fwbuf, decbuf, dec_hs);

  gemm128<0><<<dim3(227, 8), blk, 0, stream>>>(
      dec_hs, W_pred, nullptr, out, 1024, 28996, 1024, 0, 0);
}